// Round 2
// baseline (1458.243 us; speedup 1.0000x reference)
//
#include <hip/hip_runtime.h>
#include <math.h>

#define NN 100000
#define NE 1600000
#define Dd 8
#define EFF 11      // SE + 1 + D
#define EPS_BN 1e-5f
#define EPS_NORM 1e-12f
#define SLOPE 0.01f
#define STATS_BLOCKS 512

__device__ __forceinline__ float fast_tanh(float x) {
    // tanh(x) = 1 - 2/(exp(2x)+1); exact saturation at +-inf
    float t = __expf(2.0f * x);
    return 1.0f - 2.0f / (t + 1.0f);
}

// Pass 1: per-block partial sums of e-moments (77 scalars) + in-degree counts.
__global__ void __launch_bounds__(256) stats_kernel(
    const float* __restrict__ v,
    const int* __restrict__ ei,
    const float* __restrict__ ea,
    float* __restrict__ partials,   // [STATS_BLOCKS][77]
    float* __restrict__ cnt)        // [NN]
{
    float acc[77];
#pragma unroll
    for (int i = 0; i < 77; ++i) acc[i] = 0.0f;

    int tid = blockIdx.x * blockDim.x + threadIdx.x;
    int stride = gridDim.x * blockDim.x;
    for (int eidx = tid; eidx < NE; eidx += stride) {
        int s = ei[eidx];
        int d = ei[NE + eidx];
        float e[EFF];
        float2 a2 = *(const float2*)(ea + 2 * (size_t)eidx);
        e[0] = a2.x;
        e[1] = a2.y;
        float4 s0 = *(const float4*)(v + (size_t)s * Dd);
        float4 s1 = *(const float4*)(v + (size_t)s * Dd + 4);
        float4 d0 = *(const float4*)(v + (size_t)d * Dd);
        float4 d1 = *(const float4*)(v + (size_t)d * Dd + 4);
        float diff[Dd];
        diff[0] = d0.x - s0.x; diff[1] = d0.y - s0.y;
        diff[2] = d0.z - s0.z; diff[3] = d0.w - s0.w;
        diff[4] = d1.x - s1.x; diff[5] = d1.y - s1.y;
        diff[6] = d1.z - s1.z; diff[7] = d1.w - s1.w;
        float nsq = 0.0f;
#pragma unroll
        for (int i = 0; i < Dd; ++i) nsq = fmaf(diff[i], diff[i], nsq);
        float nrm = sqrtf(nsq);
        e[2] = nrm;
        float inv = 1.0f / (nrm + EPS_NORM);
#pragma unroll
        for (int i = 0; i < Dd; ++i) e[3 + i] = diff[i] * inv;

        int p = EFF;
#pragma unroll
        for (int k = 0; k < EFF; ++k) {
            acc[k] += e[k];
#pragma unroll
            for (int l = k; l < EFF; ++l) { acc[p] = fmaf(e[k], e[l], acc[p]); ++p; }
        }
        unsafeAtomicAdd(&cnt[d], 1.0f);
    }

    // wave butterfly reduce, then cross-wave via LDS, write block partial
#pragma unroll
    for (int i = 0; i < 77; ++i) {
        float x = acc[i];
        for (int off = 32; off > 0; off >>= 1) x += __shfl_down(x, off);
        acc[i] = x;
    }
    __shared__ float lsum[4][77];
    int wave = threadIdx.x >> 6;
    int lane = threadIdx.x & 63;
    if (lane == 0) {
#pragma unroll
        for (int i = 0; i < 77; ++i) lsum[wave][i] = acc[i];
    }
    __syncthreads();
    if (threadIdx.x < 77) {
        float t = lsum[0][threadIdx.x] + lsum[1][threadIdx.x]
                + lsum[2][threadIdx.x] + lsum[3][threadIdx.x];
        partials[blockIdx.x * 77 + threadIdx.x] = t;
    }
}

// Pass 2: reduce partials, finalize BN closed-form, fold scale into W/bias.
__global__ void bn_finalize_kernel(
    const float* __restrict__ partials,
    const float* __restrict__ w0, const float* __restrict__ b0,
    const float* __restrict__ g0, const float* __restrict__ be0,
    const float* __restrict__ w1, const float* __restrict__ b1,
    const float* __restrict__ g1, const float* __restrict__ be1,
    float* __restrict__ wbp)   // layer l at +l*768: W'[704] then b'[64]
{
    __shared__ double gs[77];
    int t = threadIdx.x;
    if (t < 77) {
        double s = 0.0;
        for (int b = 0; b < STATS_BLOCKS; ++b) s += (double)partials[b * 77 + t];
        gs[t] = s;
    }
    __syncthreads();
    if (t >= 128) return;
    int layer = t >> 6;
    int c = t & 63;
    const float* W  = layer ? w1 : w0;
    const float* B  = layer ? b1 : b0;
    const float* G  = layer ? g1 : g0;
    const float* BE = layer ? be1 : be0;

    const double invE = 1.0 / (double)NE;
    double m[EFF], wv[EFF];
    for (int k = 0; k < EFF; ++k) {
        m[k] = gs[k] * invE;
        wv[k] = (double)W[k * 64 + c];
    }
    double md = 0.0;
    for (int k = 0; k < EFF; ++k) md += m[k] * wv[k];
    double s2 = 0.0;
    int p = EFF;
    for (int k = 0; k < EFF; ++k)
        for (int l = k; l < EFF; ++l) {
            double Me = gs[p] * invE; ++p;
            double term = Me * wv[k] * wv[l];
            s2 += (k == l) ? term : 2.0 * term;
        }
    double var = s2 - md * md;          // variance of h col c (bias-invariant)
    double mu = md + (double)B[c];      // mean of h col c
    float scale = (float)((double)G[c] / sqrt(var + (double)EPS_BN));
    float shift = (float)((double)BE[c] - mu * (double)scale);

    float* wpd = wbp + layer * 768;
    for (int k = 0; k < EFF; ++k) wpd[k * 64 + c] = W[k * 64 + c] * scale;
    wpd[704 + c] = fmaf(B[c], scale, shift);   // b' = B*scale + shift
}

// Pass 3 (per layer): per-edge h=e@W'+b', tanh, msg = x[src]·w, atomic agg[dst].
__global__ void __launch_bounds__(256) msg_kernel(
    const float* __restrict__ vres,
    const float* __restrict__ x,
    const int* __restrict__ ei,
    const float* __restrict__ ea,
    const float* __restrict__ wb,   // [768]: W'[11*64] then b'[64]
    float* __restrict__ agg)        // [NN*8]
{
    __shared__ float wsm[768];
    for (int i = threadIdx.x; i < 768; i += 256) wsm[i] = wb[i];
    __syncthreads();

    int eidx = blockIdx.x * blockDim.x + threadIdx.x;
    if (eidx >= NE) return;
    int s = ei[eidx];
    int d = ei[NE + eidx];

    float e[EFF];
    float2 a2 = *(const float2*)(ea + 2 * (size_t)eidx);
    e[0] = a2.x;
    e[1] = a2.y;
    float4 s0 = *(const float4*)(vres + (size_t)s * Dd);
    float4 s1 = *(const float4*)(vres + (size_t)s * Dd + 4);
    float4 d0 = *(const float4*)(vres + (size_t)d * Dd);
    float4 d1 = *(const float4*)(vres + (size_t)d * Dd + 4);
    float diff[Dd];
    diff[0] = d0.x - s0.x; diff[1] = d0.y - s0.y;
    diff[2] = d0.z - s0.z; diff[3] = d0.w - s0.w;
    diff[4] = d1.x - s1.x; diff[5] = d1.y - s1.y;
    diff[6] = d1.z - s1.z; diff[7] = d1.w - s1.w;
    float nsq = 0.0f;
#pragma unroll
    for (int i = 0; i < Dd; ++i) nsq = fmaf(diff[i], diff[i], nsq);
    float nrm = sqrtf(nsq);
    e[2] = nrm;
    float inv = 1.0f / (nrm + EPS_NORM);
#pragma unroll
    for (int i = 0; i < Dd; ++i) e[3 + i] = diff[i] * inv;

    float xs[Dd];
    float4 x0 = *(const float4*)(x + (size_t)s * Dd);
    float4 x1 = *(const float4*)(x + (size_t)s * Dd + 4);
    xs[0] = x0.x; xs[1] = x0.y; xs[2] = x0.z; xs[3] = x0.w;
    xs[4] = x1.x; xs[5] = x1.y; xs[6] = x1.z; xs[7] = x1.w;

    float msg[Dd];
#pragma unroll
    for (int o = 0; o < Dd; ++o) msg[o] = 0.0f;

#pragma unroll
    for (int i = 0; i < Dd; ++i) {
#pragma unroll
        for (int o = 0; o < Dd; ++o) {
            const int c = i * 8 + o;
            float h = wsm[704 + c];
#pragma unroll
            for (int k = 0; k < EFF; ++k) h = fmaf(e[k], wsm[k * 64 + c], h);
            msg[o] = fmaf(xs[i], fast_tanh(h), msg[o]);
        }
    }

    float* ap = agg + (size_t)d * Dd;
#pragma unroll
    for (int o = 0; o < Dd; ++o) unsafeAtomicAdd(&ap[o], msg[o]);
}

// Pass 4 (per layer): out = lrelu(agg/max(cnt,1) + x@root_w + root_b) [+ vres]
__global__ void __launch_bounds__(256) node_kernel(
    const float* __restrict__ x,
    const float* __restrict__ agg,
    const float* __restrict__ cnt,
    const float* __restrict__ rw,   // [8*8]
    const float* __restrict__ rb,   // [8]
    const float* __restrict__ vres,
    float* __restrict__ out,
    int addres)
{
    int n = blockIdx.x * blockDim.x + threadIdx.x;
    if (n >= NN) return;
    float xs[Dd];
#pragma unroll
    for (int i = 0; i < Dd; ++i) xs[i] = x[(size_t)n * Dd + i];
    float c = cnt[n];
    float invc = 1.0f / fmaxf(c, 1.0f);
#pragma unroll
    for (int o = 0; o < Dd; ++o) {
        float a = fmaf(agg[(size_t)n * Dd + o], invc, rb[o]);
#pragma unroll
        for (int i = 0; i < Dd; ++i) a = fmaf(xs[i], rw[i * 8 + o], a);
        float y = (a > 0.0f) ? a : SLOPE * a;
        if (addres) y += vres[(size_t)n * Dd + o];
        out[(size_t)n * Dd + o] = y;
    }
}

extern "C" void kernel_launch(void* const* d_in, const int* in_sizes, int n_in,
                              void* d_out, int out_size, void* d_ws, size_t ws_size,
                              hipStream_t stream) {
    const float* v  = (const float*)d_in[0];
    const int* ei   = (const int*)d_in[1];      // harness passes integers as int32
    const float* ea = (const float*)d_in[2];
    const float* en_w0  = (const float*)d_in[3];
    const float* en_b0  = (const float*)d_in[4];
    const float* en_g0  = (const float*)d_in[5];
    const float* en_be0 = (const float*)d_in[6];
    const float* rw0    = (const float*)d_in[7];
    const float* rb0    = (const float*)d_in[8];
    const float* en_w1  = (const float*)d_in[9];
    const float* en_b1  = (const float*)d_in[10];
    const float* en_g1  = (const float*)d_in[11];
    const float* en_be1 = (const float*)d_in[12];
    const float* rw1    = (const float*)d_in[13];
    const float* rb1    = (const float*)d_in[14];

    char* ws = (char*)d_ws;
    float* partials = (float*)ws;                      // 512*77 f32 = 157,696 B
    float* wbp      = (float*)(ws + 163840);           // 1536 f32
    float* cnt      = (float*)(ws + 172032);           // NN f32 = 400,000 B
    float* agg      = (float*)(ws + 573440);           // NN*8 f32 = 3.2 MB
    float* vout     = (float*)d_out;

    hipMemsetAsync(cnt, 0, NN * sizeof(float), stream);
    hipMemsetAsync(agg, 0, (size_t)NN * 8 * sizeof(float), stream);

    stats_kernel<<<STATS_BLOCKS, 256, 0, stream>>>(v, ei, ea, partials, cnt);
    bn_finalize_kernel<<<1, 128, 0, stream>>>(partials, en_w0, en_b0, en_g0, en_be0,
                                              en_w1, en_b1, en_g1, en_be1, wbp);

    const int EB = (NE + 255) / 256;
    const int NB = (NN + 255) / 256;

    // layer 0: x = v, out -> d_out (used as v1 storage)
    msg_kernel<<<EB, 256, 0, stream>>>(v, v, ei, ea, wbp, agg);
    node_kernel<<<NB, 256, 0, stream>>>(v, agg, cnt, rw0, rb0, v, vout, 0);

    // layer 1: x = v1 (in d_out), out = lrelu(...) + vres -> d_out
    hipMemsetAsync(agg, 0, (size_t)NN * 8 * sizeof(float), stream);
    msg_kernel<<<EB, 256, 0, stream>>>(v, vout, ei, ea, wbp + 768, agg);
    node_kernel<<<NB, 256, 0, stream>>>(vout, agg, cnt, rw1, rb1, v, vout, 1);
}

// Round 3
// 558.575 us; speedup vs baseline: 2.6106x; 2.6106x over previous
//
#include <hip/hip_runtime.h>
#include <math.h>

#define NN 100000
#define NE 1600000
#define EPS_BN 1e-5f
#define EPS_NORM 1e-12f
#define SLOPE 0.01f
#define STATS_BLOCKS 512

__device__ __forceinline__ float fast_tanh(float x) {
    // tanh(x) = 1 - 2/(exp(2x)+1); exact saturation at +-inf
    float t = __expf(2.0f * x);
    return fmaf(-2.0f, __builtin_amdgcn_rcpf(t + 1.0f), 1.0f);
}

// Pass 1: e-moment partials (77 scalars/block) + in-degree + stable-ish rank.
__global__ void __launch_bounds__(256) stats_kernel(
    const float* __restrict__ v,
    const int* __restrict__ ei,
    const float* __restrict__ ea,
    float* __restrict__ partials,   // [STATS_BLOCKS][77]
    int* __restrict__ deg,          // [NN] (pre-zeroed)
    int* __restrict__ rank)         // [NE]
{
    float acc[77];
#pragma unroll
    for (int i = 0; i < 77; ++i) acc[i] = 0.0f;

    int tid = blockIdx.x * blockDim.x + threadIdx.x;
    int stride = gridDim.x * blockDim.x;
    for (int eidx = tid; eidx < NE; eidx += stride) {
        int s = ei[eidx];
        int d = ei[NE + eidx];
        rank[eidx] = atomicAdd(&deg[d], 1);

        float e[11];
        float2 a2 = *(const float2*)(ea + 2 * (size_t)eidx);
        e[0] = a2.x;
        e[1] = a2.y;
        float4 s0 = *(const float4*)(v + (size_t)s * 8);
        float4 s1 = *(const float4*)(v + (size_t)s * 8 + 4);
        float4 d0 = *(const float4*)(v + (size_t)d * 8);
        float4 d1 = *(const float4*)(v + (size_t)d * 8 + 4);
        float df[8];
        df[0] = d0.x - s0.x; df[1] = d0.y - s0.y;
        df[2] = d0.z - s0.z; df[3] = d0.w - s0.w;
        df[4] = d1.x - s1.x; df[5] = d1.y - s1.y;
        df[6] = d1.z - s1.z; df[7] = d1.w - s1.w;
        float nsq = 0.0f;
#pragma unroll
        for (int i = 0; i < 8; ++i) nsq = fmaf(df[i], df[i], nsq);
        float nrm = sqrtf(nsq);
        e[2] = nrm;
        float inv = __builtin_amdgcn_rcpf(nrm + EPS_NORM);
#pragma unroll
        for (int i = 0; i < 8; ++i) e[3 + i] = df[i] * inv;

        int p = 11;
#pragma unroll
        for (int k = 0; k < 11; ++k) {
            acc[k] += e[k];
#pragma unroll
            for (int l = k; l < 11; ++l) { acc[p] = fmaf(e[k], e[l], acc[p]); ++p; }
        }
    }

#pragma unroll
    for (int i = 0; i < 77; ++i) {
        float x = acc[i];
        for (int off = 32; off > 0; off >>= 1) x += __shfl_down(x, off);
        acc[i] = x;
    }
    __shared__ float lsum[4][77];
    int wave = threadIdx.x >> 6;
    int lane = threadIdx.x & 63;
    if (lane == 0) {
#pragma unroll
        for (int i = 0; i < 77; ++i) lsum[wave][i] = acc[i];
    }
    __syncthreads();
    if (threadIdx.x < 77) {
        float t = lsum[0][threadIdx.x] + lsum[1][threadIdx.x]
                + lsum[2][threadIdx.x] + lsum[3][threadIdx.x];
        partials[blockIdx.x * 77 + threadIdx.x] = t;
    }
}

// Pass 2: reduce partials, closed-form BN, fold scale into W' and b'.
__global__ void bn_finalize_kernel(
    const float* __restrict__ partials,
    const float* __restrict__ w0, const float* __restrict__ b0,
    const float* __restrict__ g0, const float* __restrict__ be0,
    const float* __restrict__ w1, const float* __restrict__ b1,
    const float* __restrict__ g1, const float* __restrict__ be1,
    float* __restrict__ wbp)   // layer l at +l*768: W'[704] then b'[64]
{
    __shared__ double gs[77];
    int t = threadIdx.x;
    if (t < 77) {
        double s = 0.0;
        for (int b = 0; b < STATS_BLOCKS; ++b) s += (double)partials[b * 77 + t];
        gs[t] = s;
    }
    __syncthreads();
    if (t >= 128) return;
    int layer = t >> 6;
    int c = t & 63;
    const float* W  = layer ? w1 : w0;
    const float* B  = layer ? b1 : b0;
    const float* G  = layer ? g1 : g0;
    const float* BE = layer ? be1 : be0;

    const double invE = 1.0 / (double)NE;
    double m[11], wv[11];
    for (int k = 0; k < 11; ++k) {
        m[k] = gs[k] * invE;
        wv[k] = (double)W[k * 64 + c];
    }
    double md = 0.0;
    for (int k = 0; k < 11; ++k) md += m[k] * wv[k];
    double s2 = 0.0;
    int p = 11;
    for (int k = 0; k < 11; ++k)
        for (int l = k; l < 11; ++l) {
            double Me = gs[p] * invE; ++p;
            double term = Me * wv[k] * wv[l];
            s2 += (k == l) ? term : 2.0 * term;
        }
    double var = s2 - md * md;
    double mu = md + (double)B[c];
    float scale = (float)((double)G[c] / sqrt(var + (double)EPS_BN));
    float shift = (float)((double)BE[c] - mu * (double)scale);

    float* wpd = wbp + layer * 768;
    for (int k = 0; k < 11; ++k) wpd[k * 64 + c] = W[k * 64 + c] * scale;
    wpd[704 + c] = fmaf(B[c], scale, shift);
}

// Pass 3: single-block exclusive scan of deg -> rowptr.
__global__ void __launch_bounds__(1024) scan_kernel(
    const int* __restrict__ deg, int* __restrict__ rowptr)
{
    const int CH = (NN + 1023) / 1024;   // 98
    int t = threadIdx.x;
    int lo = t * CH;
    int hi = lo + CH; if (hi > NN) hi = NN;
    int s = 0;
    for (int idx = lo; idx < hi; ++idx) s += deg[idx];
    __shared__ int bs[1024];
    bs[t] = s;
    __syncthreads();
    for (int off = 1; off < 1024; off <<= 1) {
        int val = (t >= off) ? bs[t - off] : 0;
        __syncthreads();
        bs[t] += val;
        __syncthreads();
    }
    int run = (t == 0) ? 0 : bs[t - 1];
    for (int idx = lo; idx < hi; ++idx) { rowptr[idx] = run; run += deg[idx]; }
    if (t == 1023) rowptr[NN] = bs[1023];
}

// Pass 4: scatter edge records into dst-sorted order (no atomics).
__global__ void __launch_bounds__(256) scatter_kernel(
    const int* __restrict__ ei, const int* __restrict__ rowptr,
    const int* __restrict__ rank, int2* __restrict__ recs)
{
    int e = blockIdx.x * 256 + threadIdx.x;
    if (e >= NE) return;
    int s = ei[e];
    int d = ei[NE + e];
    recs[rowptr[d] + rank[e]] = make_int2(s, e);
}

// Pass 5 (per layer): fused gather-message + mean + root + lrelu (+residual).
// 8 threads per dst node; thread handles input-row i, weights in registers.
template<int LAYER>
__global__ void __launch_bounds__(256) layer_kernel(
    const float* __restrict__ vres,
    const float* __restrict__ x,       // v for L0, v1 for L1
    const float* __restrict__ ea,
    const int2* __restrict__ recs,
    const int* __restrict__ rowptr,
    const float* __restrict__ wb,      // [768] W' then b'
    const float* __restrict__ rw, const float* __restrict__ rb,
    float* __restrict__ out)
{
    int g = blockIdx.x * 256 + threadIdx.x;   // grid sized so g < 8*NN exactly
    int n = g >> 3;
    int i = g & 7;

    float wreg[11][8];
#pragma unroll
    for (int k = 0; k < 11; ++k) {
        float4 wa = *(const float4*)(wb + k * 64 + i * 8);
        float4 wc = *(const float4*)(wb + k * 64 + i * 8 + 4);
        wreg[k][0] = wa.x; wreg[k][1] = wa.y; wreg[k][2] = wa.z; wreg[k][3] = wa.w;
        wreg[k][4] = wc.x; wreg[k][5] = wc.y; wreg[k][6] = wc.z; wreg[k][7] = wc.w;
    }
    float breg[8];
    {
        float4 ba = *(const float4*)(wb + 704 + i * 8);
        float4 bb = *(const float4*)(wb + 704 + i * 8 + 4);
        breg[0] = ba.x; breg[1] = ba.y; breg[2] = ba.z; breg[3] = ba.w;
        breg[4] = bb.x; breg[5] = bb.y; breg[6] = bb.z; breg[7] = bb.w;
    }

    float4 vd0 = *(const float4*)(vres + (size_t)n * 8);
    float4 vd1 = *(const float4*)(vres + (size_t)n * 8 + 4);
    float vd[8] = {vd0.x, vd0.y, vd0.z, vd0.w, vd1.x, vd1.y, vd1.z, vd1.w};

    float msg[8];
#pragma unroll
    for (int o = 0; o < 8; ++o) msg[o] = 0.0f;

    int rp0 = rowptr[n];
    int rp1 = rowptr[n + 1];
    for (int j = rp0; j < rp1; ++j) {
        int2 r = recs[j];
        int s = r.x;
        float2 a2 = *(const float2*)(ea + 2 * (size_t)r.y);
        float4 s0 = *(const float4*)(vres + (size_t)s * 8);
        float4 s1 = *(const float4*)(vres + (size_t)s * 8 + 4);
        float xi = x[(size_t)s * 8 + i];

        float df[8];
        df[0] = vd[0] - s0.x; df[1] = vd[1] - s0.y;
        df[2] = vd[2] - s0.z; df[3] = vd[3] - s0.w;
        df[4] = vd[4] - s1.x; df[5] = vd[5] - s1.y;
        df[6] = vd[6] - s1.z; df[7] = vd[7] - s1.w;
        float nsq = 0.0f;
#pragma unroll
        for (int q = 0; q < 8; ++q) nsq = fmaf(df[q], df[q], nsq);
        float nrm = sqrtf(nsq);
        float invn = __builtin_amdgcn_rcpf(nrm + EPS_NORM);
        float e[11];
        e[0] = a2.x; e[1] = a2.y; e[2] = nrm;
#pragma unroll
        for (int q = 0; q < 8; ++q) e[3 + q] = df[q] * invn;

#pragma unroll
        for (int o = 0; o < 8; ++o) {
            float hh = breg[o];
#pragma unroll
            for (int k = 0; k < 11; ++k) hh = fmaf(e[k], wreg[k][o], hh);
            msg[o] = fmaf(xi, fast_tanh(hh), msg[o]);
        }
    }

    // sum partial msg over the 8 lanes of this node-group
#pragma unroll
    for (int o = 0; o < 8; ++o) {
        float m = msg[o];
        m += __shfl_xor(m, 1);
        m += __shfl_xor(m, 2);
        m += __shfl_xor(m, 4);
        msg[o] = m;
    }
    // pick this lane's output column without dynamic register indexing
    float mo = msg[0];
#pragma unroll
    for (int o = 1; o < 8; ++o) if (i == o) mo = msg[o];

    float cf = (float)(rp1 - rp0);
    float invc = __builtin_amdgcn_rcpf(fmaxf(cf, 1.0f));

    float xn[8];
    if (LAYER == 0) {
#pragma unroll
        for (int q = 0; q < 8; ++q) xn[q] = vd[q];
    } else {
        float4 x0 = *(const float4*)(x + (size_t)n * 8);
        float4 x1 = *(const float4*)(x + (size_t)n * 8 + 4);
        xn[0] = x0.x; xn[1] = x0.y; xn[2] = x0.z; xn[3] = x0.w;
        xn[4] = x1.x; xn[5] = x1.y; xn[6] = x1.z; xn[7] = x1.w;
    }
    float a = fmaf(mo, invc, rb[i]);
#pragma unroll
    for (int k = 0; k < 8; ++k) a = fmaf(xn[k], rw[k * 8 + i], a);
    float y = (a > 0.0f) ? a : SLOPE * a;
    if (LAYER == 1) y += vres[(size_t)n * 8 + i];
    out[(size_t)n * 8 + i] = y;
}

extern "C" void kernel_launch(void* const* d_in, const int* in_sizes, int n_in,
                              void* d_out, int out_size, void* d_ws, size_t ws_size,
                              hipStream_t stream) {
    const float* v  = (const float*)d_in[0];
    const int* ei   = (const int*)d_in[1];
    const float* ea = (const float*)d_in[2];
    const float* en_w0  = (const float*)d_in[3];
    const float* en_b0  = (const float*)d_in[4];
    const float* en_g0  = (const float*)d_in[5];
    const float* en_be0 = (const float*)d_in[6];
    const float* rw0    = (const float*)d_in[7];
    const float* rb0    = (const float*)d_in[8];
    const float* en_w1  = (const float*)d_in[9];
    const float* en_b1  = (const float*)d_in[10];
    const float* en_g1  = (const float*)d_in[11];
    const float* en_be1 = (const float*)d_in[12];
    const float* rw1    = (const float*)d_in[13];
    const float* rb1    = (const float*)d_in[14];

    char* ws = (char*)d_ws;
    float* partials = (float*)(ws);                   // 512*77*4 = 157,696 B
    float* wbp      = (float*)(ws + 200704);          // 1536*4 = 6,144 B
    int*   deg      = (int*)  (ws + 208896);          // 400,000 B
    int*   rowptr   = (int*)  (ws + 618496);          // 400,004 B
    int*   rank     = (int*)  (ws + 1048576);         // 6,400,000 B
    float* v1       = (float*)(ws + 8388608);         // 3,200,000 B
    int2*  recs     = (int2*) (ws + 12582912);        // 12,800,000 B (end ~25.4 MB)
    float* vout     = (float*)d_out;

    hipMemsetAsync(deg, 0, NN * sizeof(int), stream);

    stats_kernel<<<STATS_BLOCKS, 256, 0, stream>>>(v, ei, ea, partials, deg, rank);
    scan_kernel<<<1, 1024, 0, stream>>>(deg, rowptr);
    scatter_kernel<<<(NE + 255) / 256, 256, 0, stream>>>(ei, rowptr, rank, recs);
    bn_finalize_kernel<<<1, 128, 0, stream>>>(partials, en_w0, en_b0, en_g0, en_be0,
                                              en_w1, en_b1, en_g1, en_be1, wbp);

    const int LB = (NN * 8) / 256;   // 3125, exact
    layer_kernel<0><<<LB, 256, 0, stream>>>(v, v,  ea, recs, rowptr, wbp,       rw0, rb0, v1);
    layer_kernel<1><<<LB, 256, 0, stream>>>(v, v1, ea, recs, rowptr, wbp + 768, rw1, rb1, vout);
}

// Round 4
// 404.270 us; speedup vs baseline: 3.6071x; 1.3817x over previous
//
#include <hip/hip_runtime.h>
#include <math.h>

#define NN 100000
#define NE 1600000
#define EPS_BN 1e-5f
#define EPS_NORM 1e-12f
#define SLOPE 0.01f
#define STATS_BLOCKS 512
#define SCAN_BLOCKS ((NN + 255) / 256)   // 391

__device__ __forceinline__ float fast_tanh(float x) {
    // tanh(x) = 1 - 2/(exp(2x)+1); exact saturation at +-inf
    float t = __expf(2.0f * x);
    return fmaf(-2.0f, __builtin_amdgcn_rcpf(t + 1.0f), 1.0f);
}

// Pass 1: e-moment partials (77 scalars/block) + in-degree + stable rank.
__global__ void __launch_bounds__(256) stats_kernel(
    const float* __restrict__ v,
    const int* __restrict__ ei,
    const float* __restrict__ ea,
    float* __restrict__ partials,   // [STATS_BLOCKS][77]
    int* __restrict__ deg,          // [NN] (pre-zeroed)
    int* __restrict__ rank)         // [NE]
{
    float acc[77];
#pragma unroll
    for (int i = 0; i < 77; ++i) acc[i] = 0.0f;

    int tid = blockIdx.x * blockDim.x + threadIdx.x;
    int stride = gridDim.x * blockDim.x;
    for (int eidx = tid; eidx < NE; eidx += stride) {
        int s = ei[eidx];
        int d = ei[NE + eidx];
        rank[eidx] = atomicAdd(&deg[d], 1);

        float e[11];
        float2 a2 = *(const float2*)(ea + 2 * (size_t)eidx);
        e[0] = a2.x;
        e[1] = a2.y;
        float4 s0 = *(const float4*)(v + (size_t)s * 8);
        float4 s1 = *(const float4*)(v + (size_t)s * 8 + 4);
        float4 d0 = *(const float4*)(v + (size_t)d * 8);
        float4 d1 = *(const float4*)(v + (size_t)d * 8 + 4);
        float df[8];
        df[0] = d0.x - s0.x; df[1] = d0.y - s0.y;
        df[2] = d0.z - s0.z; df[3] = d0.w - s0.w;
        df[4] = d1.x - s1.x; df[5] = d1.y - s1.y;
        df[6] = d1.z - s1.z; df[7] = d1.w - s1.w;
        float nsq = 0.0f;
#pragma unroll
        for (int i = 0; i < 8; ++i) nsq = fmaf(df[i], df[i], nsq);
        float nrm = sqrtf(nsq);
        e[2] = nrm;
        float inv = __builtin_amdgcn_rcpf(nrm + EPS_NORM);
#pragma unroll
        for (int i = 0; i < 8; ++i) e[3 + i] = df[i] * inv;

        int p = 11;
#pragma unroll
        for (int k = 0; k < 11; ++k) {
            acc[k] += e[k];
#pragma unroll
            for (int l = k; l < 11; ++l) { acc[p] = fmaf(e[k], e[l], acc[p]); ++p; }
        }
    }

#pragma unroll
    for (int i = 0; i < 77; ++i) {
        float x = acc[i];
        for (int off = 32; off > 0; off >>= 1) x += __shfl_down(x, off);
        acc[i] = x;
    }
    __shared__ float lsum[4][77];
    int wave = threadIdx.x >> 6;
    int lane = threadIdx.x & 63;
    if (lane == 0) {
#pragma unroll
        for (int i = 0; i < 77; ++i) lsum[wave][i] = acc[i];
    }
    __syncthreads();
    if (threadIdx.x < 77) {
        float t = lsum[0][threadIdx.x] + lsum[1][threadIdx.x]
                + lsum[2][threadIdx.x] + lsum[3][threadIdx.x];
        partials[blockIdx.x * 77 + threadIdx.x] = t;
    }
}

// Pass 2: reduce partials, closed-form BN, fold scale into W' and b'.
__global__ void bn_finalize_kernel(
    const float* __restrict__ partials,
    const float* __restrict__ w0, const float* __restrict__ b0,
    const float* __restrict__ g0, const float* __restrict__ be0,
    const float* __restrict__ w1, const float* __restrict__ b1,
    const float* __restrict__ g1, const float* __restrict__ be1,
    float* __restrict__ wbp)   // layer l at +l*768: W'[704] then b'[64]
{
    __shared__ double gs[77];
    int t = threadIdx.x;
    if (t < 77) {
        double s = 0.0;
        for (int b = 0; b < STATS_BLOCKS; ++b) s += (double)partials[b * 77 + t];
        gs[t] = s;
    }
    __syncthreads();
    if (t >= 128) return;
    int layer = t >> 6;
    int c = t & 63;
    const float* W  = layer ? w1 : w0;
    const float* B  = layer ? b1 : b0;
    const float* G  = layer ? g1 : g0;
    const float* BE = layer ? be1 : be0;

    const double invE = 1.0 / (double)NE;
    double m[11], wv[11];
    for (int k = 0; k < 11; ++k) {
        m[k] = gs[k] * invE;
        wv[k] = (double)W[k * 64 + c];
    }
    double md = 0.0;
    for (int k = 0; k < 11; ++k) md += m[k] * wv[k];
    double s2 = 0.0;
    int p = 11;
    for (int k = 0; k < 11; ++k)
        for (int l = k; l < 11; ++l) {
            double Me = gs[p] * invE; ++p;
            double term = Me * wv[k] * wv[l];
            s2 += (k == l) ? term : 2.0 * term;
        }
    double var = s2 - md * md;
    double mu = md + (double)B[c];
    float scale = (float)((double)G[c] / sqrt(var + (double)EPS_BN));
    float shift = (float)((double)BE[c] - mu * (double)scale);

    float* wpd = wbp + layer * 768;
    for (int k = 0; k < 11; ++k) wpd[k * 64 + c] = W[k * 64 + c] * scale;
    wpd[704 + c] = fmaf(B[c], scale, shift);
}

// Pass 3a: per-block exclusive scan of deg -> rowptr (block-local) + block sums.
__global__ void __launch_bounds__(256) scanA_kernel(
    const int* __restrict__ deg, int* __restrict__ rowptr, int* __restrict__ bsum)
{
    int b = blockIdx.x, t = threadIdx.x;
    int i = b * 256 + t;
    int d = (i < NN) ? deg[i] : 0;
    __shared__ int sh[256];
    sh[t] = d;
    __syncthreads();
    for (int off = 1; off < 256; off <<= 1) {
        int val = (t >= off) ? sh[t - off] : 0;
        __syncthreads();
        sh[t] += val;
        __syncthreads();
    }
    if (i < NN) rowptr[i] = sh[t] - d;     // exclusive within block
    if (t == 255) bsum[b] = sh[255];
}

// Pass 3b: add block offsets in-place; each block reduces bsum[0..b-1] itself.
__global__ void __launch_bounds__(256) scanC_kernel(
    int* __restrict__ rowptr, const int* __restrict__ bsum)
{
    int b = blockIdx.x, t = threadIdx.x;
    __shared__ int sh[256];
    int s = 0;
    for (int j = t; j < b; j += 256) s += bsum[j];
    sh[t] = s;
    __syncthreads();
    for (int off = 128; off > 0; off >>= 1) {
        if (t < off) sh[t] += sh[t + off];
        __syncthreads();
    }
    int boff = sh[0];
    int i = b * 256 + t;
    if (i < NN) rowptr[i] += boff;
    if (b == 0 && t == 0) rowptr[NN] = NE;   // total edge count is static
}

// Pass 4: scatter edge records into dst-sorted order (no atomics).
__global__ void __launch_bounds__(256) scatter_kernel(
    const int* __restrict__ ei, const int* __restrict__ rowptr,
    const int* __restrict__ rank, int2* __restrict__ recs)
{
    int e = blockIdx.x * 256 + threadIdx.x;
    if (e >= NE) return;
    int s = ei[e];
    int d = ei[NE + e];
    recs[rowptr[d] + rank[e]] = make_int2(s, e);
}

// Pass 5 (per layer): fused gather-message + mean + root + lrelu (+residual).
// 8 threads per dst node; thread handles input-row i, weights in registers.
template<int LAYER>
__global__ void __launch_bounds__(256) layer_kernel(
    const float* __restrict__ vres,
    const float* __restrict__ x,       // v for L0, v1 for L1
    const float* __restrict__ ea,
    const int2* __restrict__ recs,
    const int* __restrict__ rowptr,
    const float* __restrict__ wb,      // [768] W' then b'
    const float* __restrict__ rw, const float* __restrict__ rb,
    float* __restrict__ out)
{
    int g = blockIdx.x * 256 + threadIdx.x;   // grid sized so g < 8*NN exactly
    int n = g >> 3;
    int i = g & 7;

    float wreg[11][8];
#pragma unroll
    for (int k = 0; k < 11; ++k) {
        float4 wa = *(const float4*)(wb + k * 64 + i * 8);
        float4 wc = *(const float4*)(wb + k * 64 + i * 8 + 4);
        wreg[k][0] = wa.x; wreg[k][1] = wa.y; wreg[k][2] = wa.z; wreg[k][3] = wa.w;
        wreg[k][4] = wc.x; wreg[k][5] = wc.y; wreg[k][6] = wc.z; wreg[k][7] = wc.w;
    }
    float breg[8];
    {
        float4 ba = *(const float4*)(wb + 704 + i * 8);
        float4 bb = *(const float4*)(wb + 704 + i * 8 + 4);
        breg[0] = ba.x; breg[1] = ba.y; breg[2] = ba.z; breg[3] = ba.w;
        breg[4] = bb.x; breg[5] = bb.y; breg[6] = bb.z; breg[7] = bb.w;
    }

    float4 vd0 = *(const float4*)(vres + (size_t)n * 8);
    float4 vd1 = *(const float4*)(vres + (size_t)n * 8 + 4);
    float vd[8] = {vd0.x, vd0.y, vd0.z, vd0.w, vd1.x, vd1.y, vd1.z, vd1.w};

    float msg[8];
#pragma unroll
    for (int o = 0; o < 8; ++o) msg[o] = 0.0f;

    int rp0 = rowptr[n];
    int rp1 = rowptr[n + 1];
    for (int j = rp0; j < rp1; ++j) {
        int2 r = recs[j];
        int s = r.x;
        float2 a2 = *(const float2*)(ea + 2 * (size_t)r.y);
        float4 s0 = *(const float4*)(vres + (size_t)s * 8);
        float4 s1 = *(const float4*)(vres + (size_t)s * 8 + 4);
        float xi = x[(size_t)s * 8 + i];

        float df[8];
        df[0] = vd[0] - s0.x; df[1] = vd[1] - s0.y;
        df[2] = vd[2] - s0.z; df[3] = vd[3] - s0.w;
        df[4] = vd[4] - s1.x; df[5] = vd[5] - s1.y;
        df[6] = vd[6] - s1.z; df[7] = vd[7] - s1.w;
        float nsq = 0.0f;
#pragma unroll
        for (int q = 0; q < 8; ++q) nsq = fmaf(df[q], df[q], nsq);
        float nrm = sqrtf(nsq);
        float invn = __builtin_amdgcn_rcpf(nrm + EPS_NORM);
        float e[11];
        e[0] = a2.x; e[1] = a2.y; e[2] = nrm;
#pragma unroll
        for (int q = 0; q < 8; ++q) e[3 + q] = df[q] * invn;

#pragma unroll
        for (int o = 0; o < 8; ++o) {
            float hh = breg[o];
#pragma unroll
            for (int k = 0; k < 11; ++k) hh = fmaf(e[k], wreg[k][o], hh);
            msg[o] = fmaf(xi, fast_tanh(hh), msg[o]);
        }
    }

    // sum partial msg over the 8 lanes of this node-group
#pragma unroll
    for (int o = 0; o < 8; ++o) {
        float m = msg[o];
        m += __shfl_xor(m, 1);
        m += __shfl_xor(m, 2);
        m += __shfl_xor(m, 4);
        msg[o] = m;
    }
    // pick this lane's output column without dynamic register indexing
    float mo = msg[0];
#pragma unroll
    for (int o = 1; o < 8; ++o) if (i == o) mo = msg[o];

    float cf = (float)(rp1 - rp0);
    float invc = __builtin_amdgcn_rcpf(fmaxf(cf, 1.0f));

    float xn[8];
    if (LAYER == 0) {
#pragma unroll
        for (int q = 0; q < 8; ++q) xn[q] = vd[q];
    } else {
        float4 x0 = *(const float4*)(x + (size_t)n * 8);
        float4 x1 = *(const float4*)(x + (size_t)n * 8 + 4);
        xn[0] = x0.x; xn[1] = x0.y; xn[2] = x0.z; xn[3] = x0.w;
        xn[4] = x1.x; xn[5] = x1.y; xn[6] = x1.z; xn[7] = x1.w;
    }
    float a = fmaf(mo, invc, rb[i]);
#pragma unroll
    for (int k = 0; k < 8; ++k) a = fmaf(xn[k], rw[k * 8 + i], a);
    float y = (a > 0.0f) ? a : SLOPE * a;
    if (LAYER == 1) y += vres[(size_t)n * 8 + i];
    out[(size_t)n * 8 + i] = y;
}

extern "C" void kernel_launch(void* const* d_in, const int* in_sizes, int n_in,
                              void* d_out, int out_size, void* d_ws, size_t ws_size,
                              hipStream_t stream) {
    const float* v  = (const float*)d_in[0];
    const int* ei   = (const int*)d_in[1];
    const float* ea = (const float*)d_in[2];
    const float* en_w0  = (const float*)d_in[3];
    const float* en_b0  = (const float*)d_in[4];
    const float* en_g0  = (const float*)d_in[5];
    const float* en_be0 = (const float*)d_in[6];
    const float* rw0    = (const float*)d_in[7];
    const float* rb0    = (const float*)d_in[8];
    const float* en_w1  = (const float*)d_in[9];
    const float* en_b1  = (const float*)d_in[10];
    const float* en_g1  = (const float*)d_in[11];
    const float* en_be1 = (const float*)d_in[12];
    const float* rw1    = (const float*)d_in[13];
    const float* rb1    = (const float*)d_in[14];

    char* ws = (char*)d_ws;
    float* partials = (float*)(ws);                   // 512*77*4 = 157,696 B
    float* wbp      = (float*)(ws + 200704);          // 6,144 B
    int*   deg      = (int*)  (ws + 208896);          // 400,000 B
    int*   rowptr   = (int*)  (ws + 618496);          // 400,004 B
    int*   bsum     = (int*)  (ws + 1032192);         // 1,564 B
    int*   rank     = (int*)  (ws + 1048576);         // 6,400,000 B
    float* v1       = (float*)(ws + 8388608);         // 3,200,000 B
    int2*  recs     = (int2*) (ws + 12582912);        // 12,800,000 B (end ~25.4 MB)
    float* vout     = (float*)d_out;

    hipMemsetAsync(deg, 0, NN * sizeof(int), stream);

    stats_kernel<<<STATS_BLOCKS, 256, 0, stream>>>(v, ei, ea, partials, deg, rank);
    scanA_kernel<<<SCAN_BLOCKS, 256, 0, stream>>>(deg, rowptr, bsum);
    scanC_kernel<<<SCAN_BLOCKS, 256, 0, stream>>>(rowptr, bsum);
    scatter_kernel<<<(NE + 255) / 256, 256, 0, stream>>>(ei, rowptr, rank, recs);
    bn_finalize_kernel<<<1, 128, 0, stream>>>(partials, en_w0, en_b0, en_g0, en_be0,
                                              en_w1, en_b1, en_g1, en_be1, wbp);

    const int LB = (NN * 8) / 256;   // 3125, exact
    layer_kernel<0><<<LB, 256, 0, stream>>>(v, v,  ea, recs, rowptr, wbp,       rw0, rb0, v1);
    layer_kernel<1><<<LB, 256, 0, stream>>>(v, v1, ea, recs, rowptr, wbp + 768, rw1, rb1, vout);
}